// Round 4
// baseline (17.286 us; speedup 1.0000x reference)
//
#include <hip/hip_runtime.h>

#define BB 4
#define LL 1024
#define TI 8
#define JPT 2
// 256 threads/block, each thread 2 consecutive j's -> block covers 512 j's.
// grid = (LL/512, LL/TI, BB) = (2, 128, 4) = 1024 blocks -> 4 blocks/CU,
// 16 waves/CU, 4 waves/SIMD (2x the previous occupancy).

typedef float f32x2 __attribute__((ext_vector_type(2)));

#define NEG_LOG2E -1.4426950408889634f
#if __has_builtin(__builtin_amdgcn_exp2f)
#define EXP2(x) __builtin_amdgcn_exp2f(x)
#else
#define EXP2(x) __expf((x) * 0.6931471805599453f)
#endif

struct PosData {
    f32x2 s2l, s2h;   // (sg+eps)^2, dims 0-1 / 2-3
    f32x2 cl,  ch;    // f*cos(2pi*pv*x)
    f32x2 sl,  sh2;   // f*sin(2pi*pv*x)
};

struct PosRow {       // LDS copy + timestamp
    PosData d;
    float   tt;
    float   pad;      // 56B (8B-aligned)
};

__device__ __forceinline__ void ffn4(float x,
    const float* __restrict__ W1, const float* __restrict__ b1,
    const float* __restrict__ W2, const float* __restrict__ b2, float out[4]) {
    float h[4];
#pragma unroll
    for (int d = 0; d < 4; ++d) h[d] = fmaxf(fmaf(x, W1[d], b1[d]), 0.0f);
#pragma unroll
    for (int j = 0; j < 4; ++j) {
        float a = b2[j];
#pragma unroll
        for (int d = 0; d < 4; ++d) a = fmaf(h[d], W2[d * 4 + j], a);
        out[j] = fmaxf(a, 0.0f);
    }
}

// f = be*sqrt(sg+eps) (*sqrt(2) on the i side, folded once)
template<bool R2>
__device__ __forceinline__ PosData posdata(float x,
    const float* __restrict__ Wp1, const float* __restrict__ bp1,
    const float* __restrict__ Wp2, const float* __restrict__ bp2,
    const float* __restrict__ Ws1, const float* __restrict__ bs1,
    const float* __restrict__ Ws2, const float* __restrict__ bs2,
    const float* __restrict__ Wb1, const float* __restrict__ bb1,
    const float* __restrict__ Wb2, const float* __restrict__ bb2)
{
    float pv[4], sg[4], bv[4];
    ffn4(x, Wp1, bp1, Wp2, bp2, pv);
    ffn4(x, Ws1, bs1, Ws2, bs2, sg);
    ffn4(x, Wb1, bb1, Wb2, bb2, bv);
    float cc[4], ss[4], s2[4];
#pragma unroll
    for (int d = 0; d < 4; ++d) {
        float qp = 6.283185307179586f * pv[d] * x;
        float s, c;
        __sincosf(qp, &s, &c);
        float sq = sg[d] + 1e-6f;
        float f  = bv[d] * sqrtf(sq);
        if (R2) f *= 1.41421356237309505f;
        s2[d] = sq * sq;
        cc[d] = f * c;
        ss[d] = f * s;
    }
    PosData r;
    r.s2l = f32x2{s2[0], s2[1]}; r.s2h = f32x2{s2[2], s2[3]};
    r.cl  = f32x2{cc[0], cc[1]}; r.ch  = f32x2{cc[2], cc[3]};
    r.sl  = f32x2{ss[0], ss[1]}; r.sh2 = f32x2{ss[2], ss[3]};
    return r;
}

__device__ __forceinline__ f32x2 pair_term(f32x2 s2i, f32x2 s2j,
                                           f32x2 ci, f32x2 cj,
                                           f32x2 si, f32x2 sj,
                                           f32x2 ntd2l, f32x2 acc)
{
    f32x2 den = s2i + s2j;
    f32x2 rs; rs.x = rsqrtf(den.x); rs.y = rsqrtf(den.y);
    f32x2 rs2 = rs * rs;
    f32x2 arg = ntd2l * rs2;
    f32x2 e; e.x = EXP2(arg.x); e.y = EXP2(arg.y);
    f32x2 cv = __builtin_elementwise_fma(ci, cj, si * sj);
    return __builtin_elementwise_fma(rs * e, cv, acc);
}

__global__ __launch_bounds__(256) void fused_kernel(const float* __restrict__ t,
    const float* __restrict__ Wp1, const float* __restrict__ bp1,
    const float* __restrict__ Wp2, const float* __restrict__ bp2,
    const float* __restrict__ Ws1, const float* __restrict__ bs1,
    const float* __restrict__ Ws2, const float* __restrict__ bs2,
    const float* __restrict__ Wb1, const float* __restrict__ bb1,
    const float* __restrict__ Wb2, const float* __restrict__ bb2,
    float* __restrict__ out)
{
    __shared__ PosRow rows[TI];

    const int tid = threadIdx.x;
    const int b   = blockIdx.z;
    const int i0  = blockIdx.y * TI;
    const int j0  = blockIdx.x * (256 * JPT) + tid * JPT;

    if (tid < TI) {
        float xi = t[b * LL + i0 + tid];
        rows[tid].d  = posdata<true>(xi, Wp1, bp1, Wp2, bp2, Ws1, bs1, Ws2, bs2,
                                     Wb1, bb1, Wb2, bb2);
        rows[tid].tt = xi;
    }

    float tj[JPT];
    PosData jd[JPT];
#pragma unroll
    for (int jj = 0; jj < JPT; ++jj) {
        tj[jj] = t[b * LL + j0 + jj];
        jd[jj] = posdata<false>(tj[jj], Wp1, bp1, Wp2, bp2, Ws1, bs1, Ws2, bs2,
                                Wb1, bb1, Wb2, bb2);
    }

    __syncthreads();

    float* obase = out + ((size_t)b * LL + i0) * LL + j0;

#pragma unroll
    for (int ii = 0; ii < TI; ++ii) {
        PosRow rw = rows[ii];
        float res[JPT];
#pragma unroll
        for (int jj = 0; jj < JPT; ++jj) {
            float td = rw.tt - tj[jj];
            float n  = td * td * NEG_LOG2E;      // -log2(e)*td^2, exp2 arg scale
            f32x2 ntd2l; ntd2l.x = n; ntd2l.y = n;
            f32x2 acc; acc.x = 0.0f; acc.y = 0.0f;
            acc = pair_term(rw.d.s2l, jd[jj].s2l, rw.d.cl, jd[jj].cl,
                            rw.d.sl,  jd[jj].sl,  ntd2l, acc);
            acc = pair_term(rw.d.s2h, jd[jj].s2h, rw.d.ch, jd[jj].ch,
                            rw.d.sh2, jd[jj].sh2, ntd2l, acc);
            res[jj] = acc.x + acc.y;
        }
        *reinterpret_cast<float2*>(obase + (size_t)ii * LL) = make_float2(res[0], res[1]);
    }
}

extern "C" void kernel_launch(void* const* d_in, const int* in_sizes, int n_in,
                              void* d_out, int out_size, void* d_ws, size_t ws_size,
                              hipStream_t stream) {
    const float* t   = (const float*)d_in[0];
    const float* Wp1 = (const float*)d_in[1];
    const float* bp1 = (const float*)d_in[2];
    const float* Wp2 = (const float*)d_in[3];
    const float* bp2 = (const float*)d_in[4];
    const float* Ws1 = (const float*)d_in[5];
    const float* bs1 = (const float*)d_in[6];
    const float* Ws2 = (const float*)d_in[7];
    const float* bs2 = (const float*)d_in[8];
    const float* Wb1 = (const float*)d_in[9];
    const float* bb1 = (const float*)d_in[10];
    const float* Wb2 = (const float*)d_in[11];
    const float* bb2 = (const float*)d_in[12];
    float* out = (float*)d_out;

    dim3 grid(LL / (256 * JPT), LL / TI, BB);  // (2, 128, 4)
    hipLaunchKernelGGL(fused_kernel, grid, dim3(256), 0, stream,
                       t, Wp1, bp1, Wp2, bp2, Ws1, bs1, Ws2, bs2,
                       Wb1, bb1, Wb2, bb2, out);
}